// Round 12
// baseline (1457.531 us; speedup 1.0000x reference)
//
#include <hip/hip_runtime.h>
#include <hip/hip_bf16.h>

#define Bn 256
#define Tn 1024
#define Dn 64
#define Hn 128
#define G3 384
#define ICn 100
#define BT 16
#define NTH 512
#define LDH 136    // both kernels; 16B-aligned reads, write conflicts fixed by XOR swizzle
#define LDX 72

typedef _Float16 f16;
typedef __attribute__((ext_vector_type(8))) _Float16 f16x8;
typedef __attribute__((ext_vector_type(4))) _Float16 f16x4;
typedef __attribute__((ext_vector_type(4))) float f32x4;

#define MFMA(a, b, c) __builtin_amdgcn_mfma_f32_16x16x32_f16((a), (b), (c), 0, 0, 0)

// gate scales folded into weights/biases: arg_scaled = -arg/ln2 (sigmoid),
// -2*arg/ln2 (tanh) so v_exp (2^x) applies with no range-reduction mul.
#define S_SIG  (-1.4426950408889634f)
#define S_TANH (-2.8853900817779268f)
#define S_EXP  ( 1.4426950408889634f)

__device__ __forceinline__ float rcpa(float x) { return __builtin_amdgcn_rcpf(x); }
__device__ __forceinline__ float ex2(float x) {
#if __has_builtin(__builtin_amdgcn_exp2f)
    return __builtin_amdgcn_exp2f(x);
#else
    return exp2f(x);
#endif
}
__device__ __forceinline__ float sigm2(float x) { return rcpa(1.0f + ex2(x)); }
__device__ __forceinline__ float tanh2(float x) { return fmaf(2.0f, rcpa(1.0f + ex2(x)), -1.0f); }

__device__ __forceinline__ f32x4 splat4(float v) { return (f32x4){v, v, v, v}; }

// h-buffer swizzled index: element (row,col) lives at row*LDH + (col ^ ((row>>2)&3)*8).
// Writes (rows q*4+r4, col w*16+c): the 4 q-groups map to 4 disjoint 8-bank sets -> no conflict.
// Reads (row c, cols kt*32+q*8..+8): XOR keeps the 8-col block 8-aligned -> ds_read_b128 intact.
__device__ __forceinline__ int hswz(int row, int col) {
    return row * LDH + (col ^ (((row >> 2) & 3) << 3));
}

// LDS-only barrier (r11, neutral but keeps global ops un-drained)
__device__ __forceinline__ void bar_lds() {
    __builtin_amdgcn_sched_barrier(0);
    asm volatile("s_waitcnt lgkmcnt(0)" ::: "memory");
    __builtin_amdgcn_s_barrier();
    __builtin_amdgcn_sched_barrier(0);
}

// load a B^T fragment (8 contiguous k) from a row-major f32 weight, scale, cvt f16
__device__ __forceinline__ f16x8 ldw(const float* W, int row, int ldk, int k0, float s) {
    const float* p = W + (size_t)row * ldk + k0;
    f16x8 r;
#pragma unroll
    for (int j = 0; j < 8; ++j) r[j] = (f16)(p[j] * s);
    return r;
}

// ---------------- Encoder GRU (swizzled hbuf, LDH=136) ----------------
__global__ __launch_bounds__(NTH, 2)
void enc_kernel(const float* __restrict__ mu,
                const float* __restrict__ We_ih, const float* __restrict__ We_hh,
                const float* __restrict__ be_ih, const float* __restrict__ be_hh,
                float* __restrict__ h_enc)
{
    const int b0 = blockIdx.x * BT;
    const int tid = threadIdx.x;
    const int w = tid >> 6, l = tid & 63, c = l & 15, q = l >> 4;

    __shared__ f16 hbuf[2][BT * LDH];
    __shared__ f16 xstg[2][8][BT * LDX];

    const int gr = w * 16 + c, gz = Hn + w * 16 + c, gn = 2 * Hn + w * 16 + c;

    f16x8 whf[3][4], wxf[3][2];
#pragma unroll
    for (int kt = 0; kt < 4; ++kt) {
        whf[0][kt] = ldw(We_hh, gr, Hn, kt * 32 + q * 8, S_SIG);
        whf[1][kt] = ldw(We_hh, gz, Hn, kt * 32 + q * 8, S_SIG);
        whf[2][kt] = ldw(We_hh, gn, Hn, kt * 32 + q * 8, S_TANH);
    }
#pragma unroll
    for (int kt = 0; kt < 2; ++kt) {
        wxf[0][kt] = ldw(We_ih, gr, Dn, kt * 32 + q * 8, S_SIG);
        wxf[1][kt] = ldw(We_ih, gz, Dn, kt * 32 + q * 8, S_SIG);
        wxf[2][kt] = ldw(We_ih, gn, Dn, kt * 32 + q * 8, S_TANH);
    }
    const float brc = S_SIG * (be_ih[gr] + be_hh[gr]);
    const float bzc = S_SIG * (be_ih[gz] + be_hh[gz]);
    const float bxn = S_TANH * be_ih[gn];
    const float bhn = S_TANH * be_hh[gn];

    float hreg[4];
#pragma unroll
    for (int r4 = 0; r4 < 4; ++r4) hreg[r4] = 0.0f;
    for (int i = tid; i < BT * Hn; i += NTH) hbuf[0][hswz(i >> 7, i & 127)] = (f16)0.0f;

    const int SIT = (BT * 8 * Dn) / (NTH * 4);  // = 4 staging iters per 8-step chunk
#pragma unroll
    for (int i = 0; i < SIT; ++i) {
        int f = (i * NTH + tid) * 4;
        int t_off = f >> 10, rem = f & 1023;
        int bb = rem >> 6, d = rem & 63;
        const float4 v = *reinterpret_cast<const float4*>(
            mu + ((size_t)(b0 + bb) * Tn + t_off) * Dn + d);
        f16x4 h4; h4[0] = (f16)v.x; h4[1] = (f16)v.y; h4[2] = (f16)v.z; h4[3] = (f16)v.w;
        *reinterpret_cast<f16x4*>(&xstg[0][t_off][bb * LDX + d]) = h4;
    }
    __syncthreads();

    float4 pre[SIT];
    for (int t = 0; t < Tn; ++t) {
        const int ch = t >> 3, s = t & 7, cur = t & 1, sb = ch & 1;
        if (s == 0 && ch + 1 < Tn / 8) {
#pragma unroll
            for (int i = 0; i < SIT; ++i) {
                int f = (i * NTH + tid) * 4;
                int t_off = f >> 10, rem = f & 1023;
                int bb = rem >> 6, d = rem & 63;
                pre[i] = *reinterpret_cast<const float4*>(
                    mu + ((size_t)(b0 + bb) * Tn + (ch + 1) * 8 + t_off) * Dn + d);
            }
        }
        f16x8 ah[4], ax[2];
#pragma unroll
        for (int kt = 0; kt < 4; ++kt)
            ah[kt] = *reinterpret_cast<const f16x8*>(&hbuf[cur][hswz(c, kt * 32 + q * 8)]);
#pragma unroll
        for (int kt = 0; kt < 2; ++kt)
            ax[kt] = *reinterpret_cast<const f16x8*>(&xstg[sb][s][c * LDX + kt * 32 + q * 8]);

        f32x4 acc0 = splat4(brc), acc1 = splat4(bzc);
        f32x4 acc2 = splat4(bhn), accx = splat4(bxn);
        __builtin_amdgcn_s_setprio(1);
#pragma unroll
        for (int kt = 0; kt < 4; ++kt) {
            acc0 = MFMA(ah[kt], whf[0][kt], acc0);
            acc1 = MFMA(ah[kt], whf[1][kt], acc1);
            acc2 = MFMA(ah[kt], whf[2][kt], acc2);
        }
#pragma unroll
        for (int kt = 0; kt < 2; ++kt) {
            acc0 = MFMA(ax[kt], wxf[0][kt], acc0);
            acc1 = MFMA(ax[kt], wxf[1][kt], acc1);
            accx = MFMA(ax[kt], wxf[2][kt], accx);
        }
        __builtin_amdgcn_s_setprio(0);
#pragma unroll
        for (int r4 = 0; r4 < 4; ++r4) {
            float rg = sigm2(acc0[r4]);
            float zg = sigm2(acc1[r4]);
            float ng = tanh2(fmaf(rg, acc2[r4], accx[r4]));
            float hv = fmaf(zg, hreg[r4] - ng, ng);
            hreg[r4] = hv;
            hbuf[cur ^ 1][hswz(q * 4 + r4, w * 16 + c)] = (f16)hv;
        }
        if (s == 7 && ch + 1 < Tn / 8) {
#pragma unroll
            for (int i = 0; i < SIT; ++i) {
                int f = (i * NTH + tid) * 4;
                int t_off = f >> 10, rem = f & 1023;
                int bb = rem >> 6, d = rem & 63;
                f16x4 h4;
                h4[0] = (f16)pre[i].x; h4[1] = (f16)pre[i].y;
                h4[2] = (f16)pre[i].z; h4[3] = (f16)pre[i].w;
                *reinterpret_cast<f16x4*>(&xstg[sb ^ 1][t_off][bb * LDX + d]) = h4;
            }
        }
        bar_lds();
    }
#pragma unroll
    for (int r4 = 0; r4 < 4; ++r4)
        h_enc[(size_t)(b0 + q * 4 + r4) * Hn + w * 16 + c] = hreg[r4];
}

// ---------------- Generator GRU (swizzled hbuf, LDH=136) ----------------
__global__ __launch_bounds__(NTH, 2)
void gen_kernel(const float* __restrict__ h_enc,
                const float* __restrict__ W_ic, const float* __restrict__ b_ic,
                const float* __restrict__ Wg_ih, const float* __restrict__ Wg_hh,
                const float* __restrict__ bg_ih, const float* __restrict__ bg_hh,
                const float* __restrict__ W_gf, const float* __restrict__ b_gf,
                const float* __restrict__ W_fr, const float* __restrict__ b_fr,
                float* __restrict__ out)
{
    const int b0 = blockIdx.x * BT;
    const int tid = threadIdx.x;
    const int w = tid >> 6, l = tid & 63, c = l & 15, q = l >> 4;

    __shared__ f16 hbuf[2][BT * LDH];
    __shared__ float hencs[BT][Hn];
    __shared__ float ics[BT][ICn];
    __shared__ float xpcs[BT][G3];
    __shared__ float fredB[2][8][BT][4];   // [blk parity][slot][batch][factor]

    for (int i = tid; i < BT * Hn; i += NTH)
        hencs[i >> 7][i & 127] = h_enc[(size_t)(b0 + (i >> 7)) * Hn + (i & 127)];
    __syncthreads();

    for (int i = tid; i < BT * ICn; i += NTH) {
        int bb = i / ICn, j = i - bb * ICn;
        float a = b_ic[j];
        const float* wr = W_ic + (size_t)j * Hn;
#pragma unroll 4
        for (int k = 0; k < Hn; ++k) a = fmaf(wr[k], hencs[bb][k], a);
        ics[bb][j] = a;
    }
    __syncthreads();

    for (int i = tid; i < BT * G3; i += NTH) {
        int g = i >> 4, bb = i & 15;
        float a = bg_ih[g];
        const float* wr = Wg_ih + (size_t)g * ICn;
#pragma unroll 4
        for (int k = 0; k < ICn; ++k) a = fmaf(wr[k], ics[bb][k], a);
        xpcs[bb][g] = a;
    }
    for (int i = tid; i < BT * Hn; i += NTH)
        hbuf[0][hswz(i >> 7, i & 127)] = (f16)hencs[i >> 7][i & 127];

    const int gr = w * 16 + c, gz = Hn + w * 16 + c, gn = 2 * Hn + w * 16 + c;

    f16x8 whf[3][4];
#pragma unroll
    for (int kt = 0; kt < 4; ++kt) {
        whf[0][kt] = ldw(Wg_hh, gr, Hn, kt * 32 + q * 8, S_SIG);
        whf[1][kt] = ldw(Wg_hh, gz, Hn, kt * 32 + q * 8, S_SIG);
        whf[2][kt] = ldw(Wg_hh, gn, Hn, kt * 32 + q * 8, S_TANH);
    }
    // every wave holds the readout fragments (round-robin), scaled for ex2
    f16x8 wgff[4];
#pragma unroll
    for (int kt = 0; kt < 4; ++kt) {
        if (c < 3) wgff[kt] = ldw(W_gf, c, Hn, kt * 32 + q * 8, S_EXP);
        else {
            f16x8 z;
#pragma unroll
            for (int j = 0; j < 8; ++j) z[j] = (f16)0.0f;
            wgff[kt] = z;
        }
    }
    const float bgfc = (c < 3) ? S_EXP * b_gf[c] : 0.0f;
    const int d = l;
    const float wfr0 = W_fr[d * 3 + 0], wfr1 = W_fr[d * 3 + 1], wfr2 = W_fr[d * 3 + 2];
    const float bfrd = b_fr[d];
    float* op0 = out + ((size_t)(b0 + w) * Tn) * Dn + d;
    float* op1 = out + ((size_t)(b0 + w + 8) * Tn) * Dn + d;

    float hreg[4];
#pragma unroll
    for (int r4 = 0; r4 < 4; ++r4) hreg[r4] = hencs[q * 4 + r4][w * 16 + c];

    __syncthreads();  // xpcs + hbuf[0] ready

    const float bgr = bg_hh[gr], bgz = bg_hh[gz], bhnr = bg_hh[gn];
    f32x4 xrcv, xzcv;
    float xnc[4];
#pragma unroll
    for (int r4 = 0; r4 < 4; ++r4) {
        int bb = q * 4 + r4;
        xrcv[r4] = S_SIG * (xpcs[bb][gr] + bgr);
        xzcv[r4] = S_SIG * (xpcs[bb][gz] + bgz);
        xnc[r4] = S_TANH * xpcs[bb][gn];
    }
    const f32x4 bhnv = splat4(S_TANH * bhnr);
    const f32x4 bgfv = splat4(bgfc);

    auto step = [&](int t, const f16* hb_r, f16* hb_w) {
        const int slot = t & 7, par = (t >> 3) & 1;
        f16x8 ah[4];
#pragma unroll
        for (int kt = 0; kt < 4; ++kt)
            ah[kt] = *reinterpret_cast<const f16x8*>(&hb_r[hswz(c, kt * 32 + q * 8)]);

        f32x4 acc0 = xrcv, acc1 = xzcv, acc2 = bhnv;
        __builtin_amdgcn_s_setprio(1);
#pragma unroll
        for (int kt = 0; kt < 4; ++kt) {
            acc0 = MFMA(ah[kt], whf[0][kt], acc0);
            acc1 = MFMA(ah[kt], whf[1][kt], acc1);
            acc2 = MFMA(ah[kt], whf[2][kt], acc2);
        }
        __builtin_amdgcn_s_setprio(0);
        if (w == slot) {  // round-robin readout wave: factors of h_t -> out row t-1
            f32x4 facc = bgfv;
#pragma unroll
            for (int kt = 0; kt < 4; ++kt) facc = MFMA(ah[kt], wgff[kt], facc);
            if (c < 3) {
#pragma unroll
                for (int r4 = 0; r4 < 4; ++r4)
                    fredB[par][slot][q * 4 + r4][c] = ex2(facc[r4]);
            }
        }
#pragma unroll
        for (int r4 = 0; r4 < 4; ++r4) {
            float rg = sigm2(acc0[r4]);
            float zg = sigm2(acc1[r4]);
            float ng = tanh2(fmaf(rg, acc2[r4], xnc[r4]));
            float hv = fmaf(zg, hreg[r4] - ng, ng);
            hreg[r4] = hv;
            hb_w[hswz(q * 4 + r4, w * 16 + c)] = (f16)hv;
        }
        bar_lds();
        if (slot == 7) {  // burst: rates for out rows blk*8-1 .. blk*8+6
            const int base_row = (t >> 3) * 8 - 1;
#pragma unroll
            for (int s = 0; s < 8; ++s) {
                const int r = base_row + s;
                if (r >= 0) {
                    const float4 f0 = *reinterpret_cast<const float4*>(&fredB[par][s][w][0]);
                    op0[(size_t)r * Dn] = bfrd + f0.x * wfr0 + f0.y * wfr1 + f0.z * wfr2;
                    const float4 f1 = *reinterpret_cast<const float4*>(&fredB[par][s][w + 8][0]);
                    op1[(size_t)r * Dn] = bfrd + f1.x * wfr0 + f1.y * wfr1 + f1.z * wfr2;
                }
            }
        }
    };

    for (int tt = 0; tt < Tn; tt += 2) {
        step(tt,     hbuf[0], hbuf[1]);
        step(tt + 1, hbuf[1], hbuf[0]);
    }
    // epilogue: out row 1023 = f(h_1024), h_1024 sits in hbuf[0]
    if (w == 0) {
        f16x8 ah[4];
#pragma unroll
        for (int kt = 0; kt < 4; ++kt)
            ah[kt] = *reinterpret_cast<const f16x8*>(&hbuf[0][hswz(c, kt * 32 + q * 8)]);
        f32x4 facc = bgfv;
#pragma unroll
        for (int kt = 0; kt < 4; ++kt) facc = MFMA(ah[kt], wgff[kt], facc);
        if (c < 3) {
#pragma unroll
            for (int r4 = 0; r4 < 4; ++r4)
                fredB[0][0][q * 4 + r4][c] = ex2(facc[r4]);
        }
    }
    __syncthreads();
    {
        const size_t ofs = (size_t)(Tn - 1) * Dn;
        const float4 f0 = *reinterpret_cast<const float4*>(&fredB[0][0][w][0]);
        op0[ofs] = bfrd + f0.x * wfr0 + f0.y * wfr1 + f0.z * wfr2;
        const float4 f1 = *reinterpret_cast<const float4*>(&fredB[0][0][w + 8][0]);
        op1[ofs] = bfrd + f1.x * wfr0 + f1.y * wfr1 + f1.z * wfr2;
    }
}

extern "C" void kernel_launch(void* const* d_in, const int* in_sizes, int n_in,
                              void* d_out, int out_size, void* d_ws, size_t ws_size,
                              hipStream_t stream) {
    const float* mu    = (const float*)d_in[0];
    const float* We_ih = (const float*)d_in[1];
    const float* We_hh = (const float*)d_in[2];
    const float* be_ih = (const float*)d_in[3];
    const float* be_hh = (const float*)d_in[4];
    const float* W_ic  = (const float*)d_in[5];
    const float* b_ic  = (const float*)d_in[6];
    const float* Wg_ih = (const float*)d_in[7];
    const float* Wg_hh = (const float*)d_in[8];
    const float* bg_ih = (const float*)d_in[9];
    const float* bg_hh = (const float*)d_in[10];
    const float* W_gf  = (const float*)d_in[11];
    const float* b_gf  = (const float*)d_in[12];
    const float* W_fr  = (const float*)d_in[13];
    const float* b_fr  = (const float*)d_in[14];

    float* h_enc = (float*)d_ws;  // [B, H] f32 = 128 KiB
    float* out = (float*)d_out;

    enc_kernel<<<dim3(Bn / BT), dim3(NTH), 0, stream>>>(mu, We_ih, We_hh, be_ih, be_hh, h_enc);
    gen_kernel<<<dim3(Bn / BT), dim3(NTH), 0, stream>>>(h_enc, W_ic, b_ic, Wg_ih, Wg_hh,
                                                        bg_ih, bg_hh, W_gf, b_gf, W_fr, b_fr, out);
}

// Round 13
// 1411.898 us; speedup vs baseline: 1.0323x; 1.0323x over previous
//
#include <hip/hip_runtime.h>
#include <hip/hip_bf16.h>

#define Bn 256
#define Tn 1024
#define Dn 64
#define Hn 128
#define G3 384
#define ICn 100
#define BT 16
#define NTH 512
#define LDHE 140   // enc hbuf stride (proven, r8/r11)
#define LDHG 136   // gen ring stride (16B-aligned reads, proven)
#define LDX 72
#define SLOT (BT * LDHG)   // 2176 f16 per ring slot

typedef _Float16 f16;
typedef __attribute__((ext_vector_type(8))) _Float16 f16x8;
typedef __attribute__((ext_vector_type(4))) _Float16 f16x4;
typedef __attribute__((ext_vector_type(4))) float f32x4;

#define MFMA(a, b, c) __builtin_amdgcn_mfma_f32_16x16x32_f16((a), (b), (c), 0, 0, 0)

#define S_SIG  (-1.4426950408889634f)
#define S_TANH (-2.8853900817779268f)
#define S_EXP  ( 1.4426950408889634f)

__device__ __forceinline__ float rcpa(float x) { return __builtin_amdgcn_rcpf(x); }
__device__ __forceinline__ float ex2(float x) {
#if __has_builtin(__builtin_amdgcn_exp2f)
    return __builtin_amdgcn_exp2f(x);
#else
    return exp2f(x);
#endif
}
__device__ __forceinline__ float sigm2(float x) { return rcpa(1.0f + ex2(x)); }
__device__ __forceinline__ float tanh2(float x) { return fmaf(2.0f, rcpa(1.0f + ex2(x)), -1.0f); }
__device__ __forceinline__ f32x4 splat4(float v) { return (f32x4){v, v, v, v}; }

// LDS-only barrier (keeps global ops un-drained across steps)
__device__ __forceinline__ void bar_lds() {
    __builtin_amdgcn_sched_barrier(0);
    asm volatile("s_waitcnt lgkmcnt(0)" ::: "memory");
    __builtin_amdgcn_s_barrier();
    __builtin_amdgcn_sched_barrier(0);
}

__device__ __forceinline__ f16x8 ldw(const float* W, int row, int ldk, int k0, float s) {
    const float* p = W + (size_t)row * ldk + k0;
    f16x8 r;
#pragma unroll
    for (int j = 0; j < 8; ++j) r[j] = (f16)(p[j] * s);
    return r;
}

// ---------------- Encoder GRU (r11 verbatim — proven ~657us) ----------------
__global__ __launch_bounds__(NTH, 2)
void enc_kernel(const float* __restrict__ mu,
                const float* __restrict__ We_ih, const float* __restrict__ We_hh,
                const float* __restrict__ be_ih, const float* __restrict__ be_hh,
                float* __restrict__ h_enc)
{
    const int b0 = blockIdx.x * BT;
    const int tid = threadIdx.x;
    const int w = tid >> 6, l = tid & 63, c = l & 15, q = l >> 4;

    __shared__ f16 hbuf[2][BT * LDHE];
    __shared__ f16 xstg[2][8][BT * LDX];

    const int gr = w * 16 + c, gz = Hn + w * 16 + c, gn = 2 * Hn + w * 16 + c;

    f16x8 whf[3][4], wxf[3][2];
#pragma unroll
    for (int kt = 0; kt < 4; ++kt) {
        whf[0][kt] = ldw(We_hh, gr, Hn, kt * 32 + q * 8, S_SIG);
        whf[1][kt] = ldw(We_hh, gz, Hn, kt * 32 + q * 8, S_SIG);
        whf[2][kt] = ldw(We_hh, gn, Hn, kt * 32 + q * 8, S_TANH);
    }
#pragma unroll
    for (int kt = 0; kt < 2; ++kt) {
        wxf[0][kt] = ldw(We_ih, gr, Dn, kt * 32 + q * 8, S_SIG);
        wxf[1][kt] = ldw(We_ih, gz, Dn, kt * 32 + q * 8, S_SIG);
        wxf[2][kt] = ldw(We_ih, gn, Dn, kt * 32 + q * 8, S_TANH);
    }
    const float brc = S_SIG * (be_ih[gr] + be_hh[gr]);
    const float bzc = S_SIG * (be_ih[gz] + be_hh[gz]);
    const float bxn = S_TANH * be_ih[gn];
    const float bhn = S_TANH * be_hh[gn];

    float hreg[4];
#pragma unroll
    for (int r4 = 0; r4 < 4; ++r4) hreg[r4] = 0.0f;
    for (int i = tid; i < BT * Hn; i += NTH) hbuf[0][(i >> 7) * LDHE + (i & 127)] = (f16)0.0f;

    const int SIT = (BT * 8 * Dn) / (NTH * 4);
#pragma unroll
    for (int i = 0; i < SIT; ++i) {
        int f = (i * NTH + tid) * 4;
        int t_off = f >> 10, rem = f & 1023;
        int bb = rem >> 6, d = rem & 63;
        const float4 v = *reinterpret_cast<const float4*>(
            mu + ((size_t)(b0 + bb) * Tn + t_off) * Dn + d);
        f16x4 h4; h4[0] = (f16)v.x; h4[1] = (f16)v.y; h4[2] = (f16)v.z; h4[3] = (f16)v.w;
        *reinterpret_cast<f16x4*>(&xstg[0][t_off][bb * LDX + d]) = h4;
    }
    __syncthreads();

    float4 pre[SIT];
    for (int t = 0; t < Tn; ++t) {
        const int ch = t >> 3, s = t & 7, cur = t & 1, sb = ch & 1;
        if (s == 0 && ch + 1 < Tn / 8) {
#pragma unroll
            for (int i = 0; i < SIT; ++i) {
                int f = (i * NTH + tid) * 4;
                int t_off = f >> 10, rem = f & 1023;
                int bb = rem >> 6, d = rem & 63;
                pre[i] = *reinterpret_cast<const float4*>(
                    mu + ((size_t)(b0 + bb) * Tn + (ch + 1) * 8 + t_off) * Dn + d);
            }
        }
        f16x8 ah[4], ax[2];
#pragma unroll
        for (int kt = 0; kt < 4; ++kt)
            ah[kt] = *reinterpret_cast<const f16x8*>(&hbuf[cur][c * LDHE + kt * 32 + q * 8]);
#pragma unroll
        for (int kt = 0; kt < 2; ++kt)
            ax[kt] = *reinterpret_cast<const f16x8*>(&xstg[sb][s][c * LDX + kt * 32 + q * 8]);

        f32x4 acc0 = splat4(brc), acc1 = splat4(bzc);
        f32x4 acc2 = splat4(bhn), accx = splat4(bxn);
        __builtin_amdgcn_s_setprio(1);
#pragma unroll
        for (int kt = 0; kt < 4; ++kt) {
            acc0 = MFMA(ah[kt], whf[0][kt], acc0);
            acc1 = MFMA(ah[kt], whf[1][kt], acc1);
            acc2 = MFMA(ah[kt], whf[2][kt], acc2);
        }
#pragma unroll
        for (int kt = 0; kt < 2; ++kt) {
            acc0 = MFMA(ax[kt], wxf[0][kt], acc0);
            acc1 = MFMA(ax[kt], wxf[1][kt], acc1);
            accx = MFMA(ax[kt], wxf[2][kt], accx);
        }
        __builtin_amdgcn_s_setprio(0);
#pragma unroll
        for (int r4 = 0; r4 < 4; ++r4) {
            float rg = sigm2(acc0[r4]);
            float zg = sigm2(acc1[r4]);
            float ng = tanh2(fmaf(rg, acc2[r4], accx[r4]));
            float hv = fmaf(zg, hreg[r4] - ng, ng);
            hreg[r4] = hv;
            hbuf[cur ^ 1][(q * 4 + r4) * LDHE + w * 16 + c] = (f16)hv;
        }
        if (s == 7 && ch + 1 < Tn / 8) {
#pragma unroll
            for (int i = 0; i < SIT; ++i) {
                int f = (i * NTH + tid) * 4;
                int t_off = f >> 10, rem = f & 1023;
                int bb = rem >> 6, d = rem & 63;
                f16x4 h4;
                h4[0] = (f16)pre[i].x; h4[1] = (f16)pre[i].y;
                h4[2] = (f16)pre[i].z; h4[3] = (f16)pre[i].w;
                *reinterpret_cast<f16x4*>(&xstg[sb ^ 1][t_off][bb * LDX + d]) = h4;
            }
        }
        bar_lds();
    }
#pragma unroll
    for (int r4 = 0; r4 < 4; ++r4)
        h_enc[(size_t)(b0 + q * 4 + r4) * Hn + w * 16 + c] = hreg[r4];
}

// ---------------- Generator GRU: 8-deep h-ring + all-wave burst readout ----------------
__global__ __launch_bounds__(NTH, 2)
void gen_kernel(const float* __restrict__ h_enc,
                const float* __restrict__ W_ic, const float* __restrict__ b_ic,
                const float* __restrict__ Wg_ih, const float* __restrict__ Wg_hh,
                const float* __restrict__ bg_ih, const float* __restrict__ bg_hh,
                const float* __restrict__ W_gf, const float* __restrict__ b_gf,
                const float* __restrict__ W_fr, const float* __restrict__ b_fr,
                float* __restrict__ out)
{
    const int b0 = blockIdx.x * BT;
    const int tid = threadIdx.x;
    const int w = tid >> 6, l = tid & 63, c = l & 15, q = l >> 4;

    // One LDS arena, two lifetimes:
    //  prologue: hencs [BT*Hn]f32 | ics [BT*ICn]f32 | xpcs [BT*G3]f32   (39168 B)
    //  main:     ring  8*SLOT f16 (34816 B) | fred [8][16][4]f32 (2048 B)
    // Lifetime safety: ring[0] written (from regs) only after all prologue reads;
    // ring[1..7]/fred first written at steps 0..6 / t==7, long after prologue.
    __shared__ __align__(16) char smem[39424];
    float* hencs = (float*)smem;                 // [bb*Hn + k]
    float* ics   = hencs + BT * Hn;              // [bb*ICn + j]
    float* xpcs  = ics + BT * ICn;               // [bb*G3 + g]
    f16*   ring  = (f16*)smem;                   // [slot*SLOT + row*LDHG + col]
    float* fredp = (float*)(smem + 8 * SLOT * 2); // [(w*16+b)*4 + f]

    for (int i = tid; i < BT * Hn; i += NTH)
        hencs[(i >> 7) * Hn + (i & 127)] = h_enc[(size_t)(b0 + (i >> 7)) * Hn + (i & 127)];
    __syncthreads();

    for (int i = tid; i < BT * ICn; i += NTH) {
        int bb = i / ICn, j = i - bb * ICn;
        float a = b_ic[j];
        const float* wr = W_ic + (size_t)j * Hn;
#pragma unroll 4
        for (int k = 0; k < Hn; ++k) a = fmaf(wr[k], hencs[bb * Hn + k], a);
        ics[bb * ICn + j] = a;
    }
    __syncthreads();

    for (int i = tid; i < BT * G3; i += NTH) {
        int g = i >> 4, bb = i & 15;
        float a = bg_ih[g];
        const float* wr = Wg_ih + (size_t)g * ICn;
#pragma unroll 4
        for (int k = 0; k < ICn; ++k) a = fmaf(wr[k], ics[bb * ICn + k], a);
        xpcs[bb * G3 + g] = a;
    }
    __syncthreads();

    const int gr = w * 16 + c, gz = Hn + w * 16 + c, gn = 2 * Hn + w * 16 + c;

    f16x8 whf[3][4];
#pragma unroll
    for (int kt = 0; kt < 4; ++kt) {
        whf[0][kt] = ldw(Wg_hh, gr, Hn, kt * 32 + q * 8, S_SIG);
        whf[1][kt] = ldw(Wg_hh, gz, Hn, kt * 32 + q * 8, S_SIG);
        whf[2][kt] = ldw(Wg_hh, gn, Hn, kt * 32 + q * 8, S_TANH);
    }
    f16x8 wgff[4];
#pragma unroll
    for (int kt = 0; kt < 4; ++kt) {
        if (c < 3) wgff[kt] = ldw(W_gf, c, Hn, kt * 32 + q * 8, S_EXP);
        else {
            f16x8 z;
#pragma unroll
            for (int j = 0; j < 8; ++j) z[j] = (f16)0.0f;
            wgff[kt] = z;
        }
    }
    const float bgfc = (c < 3) ? S_EXP * b_gf[c] : 0.0f;
    const int d = l;
    const float wfr0 = W_fr[d * 3 + 0], wfr1 = W_fr[d * 3 + 1], wfr2 = W_fr[d * 3 + 2];
    const float bfrd = b_fr[d];

    float hreg[4];
#pragma unroll
    for (int r4 = 0; r4 < 4; ++r4) hreg[r4] = hencs[(q * 4 + r4) * Hn + w * 16 + c];

    const float bgr = bg_hh[gr], bgz = bg_hh[gz], bhnr = bg_hh[gn];
    f32x4 xrcv, xzcv;
    float xnc[4];
#pragma unroll
    for (int r4 = 0; r4 < 4; ++r4) {
        int bb = q * 4 + r4;
        xrcv[r4] = S_SIG * (xpcs[bb * G3 + gr] + bgr);
        xzcv[r4] = S_SIG * (xpcs[bb * G3 + gz] + bgz);
        xnc[r4] = S_TANH * xpcs[bb * G3 + gn];
    }
    const f32x4 bhnv = splat4(S_TANH * bhnr);
    const f32x4 bgfv = splat4(bgfc);

    __syncthreads();  // all prologue LDS reads done -> safe to overwrite arena
    // seed ring[0] = h_0 (from registers; arena overlap is safe now)
#pragma unroll
    for (int r4 = 0; r4 < 4; ++r4)
        ring[(q * 4 + r4) * LDHG + w * 16 + c] = (f16)hreg[r4];
    __syncthreads();

    for (int t = 0; t < Tn; ++t) {
        const int s = t & 7;
        f16x8 ah[4];
#pragma unroll
        for (int kt = 0; kt < 4; ++kt)
            ah[kt] = *reinterpret_cast<const f16x8*>(&ring[s * SLOT + c * LDHG + kt * 32 + q * 8]);

        f32x4 acc0 = xrcv, acc1 = xzcv, acc2 = bhnv;
        __builtin_amdgcn_s_setprio(1);
#pragma unroll
        for (int kt = 0; kt < 4; ++kt) {
            acc0 = MFMA(ah[kt], whf[0][kt], acc0);
            acc1 = MFMA(ah[kt], whf[1][kt], acc1);
            acc2 = MFMA(ah[kt], whf[2][kt], acc2);
        }
        __builtin_amdgcn_s_setprio(0);

        f32x4 facc = bgfv;
        if (s == 7) {
            // all-wave burst readout: wave w handles h_{t-7+w} (in ring[w])
            f16x8 rah[4];
#pragma unroll
            for (int kt = 0; kt < 4; ++kt)
                rah[kt] = *reinterpret_cast<const f16x8*>(&ring[w * SLOT + c * LDHG + kt * 32 + q * 8]);
#pragma unroll
            for (int kt = 0; kt < 4; ++kt) facc = MFMA(rah[kt], wgff[kt], facc);
        }

#pragma unroll
        for (int r4 = 0; r4 < 4; ++r4) {
            float rg = sigm2(acc0[r4]);
            float zg = sigm2(acc1[r4]);
            float ng = tanh2(fmaf(rg, acc2[r4], xnc[r4]));
            float hv = fmaf(zg, hreg[r4] - ng, ng);
            hreg[r4] = hv;
        }
        if (s == 7) bar_lds();  // drain burst reads before overwriting ring slot 0
#pragma unroll
        for (int r4 = 0; r4 < 4; ++r4)
            ring[((t + 1) & 7) * SLOT + (q * 4 + r4) * LDHG + w * 16 + c] = (f16)hreg[r4];
        bar_lds();

        if (s == 7) {
            const int row = t - 8 + w;   // out row for h_{t-7+w}
            if (c < 3) {
#pragma unroll
                for (int r4 = 0; r4 < 4; ++r4)
                    fredp[(w * 16 + q * 4 + r4) * 4 + c] = ex2(facc[r4]);
            }
            asm volatile("s_waitcnt lgkmcnt(0)" ::: "memory");  // wave-local fred ready
            if (row >= 0) {
#pragma unroll
                for (int b = 0; b < BT; ++b) {
                    const float4 f4 = *reinterpret_cast<const float4*>(&fredp[(w * 16 + b) * 4]);
                    out[((size_t)(b0 + b) * Tn + row) * Dn + d] =
                        bfrd + f4.x * wfr0 + f4.y * wfr1 + f4.z * wfr2;
                }
            }
        }
    }
    // epilogue: row 1023 from h_1024 (sits in ring[0]); wave 0 only
    if (w == 0) {
        f16x8 rah[4];
#pragma unroll
        for (int kt = 0; kt < 4; ++kt)
            rah[kt] = *reinterpret_cast<const f16x8*>(&ring[c * LDHG + kt * 32 + q * 8]);
        f32x4 facc = bgfv;
#pragma unroll
        for (int kt = 0; kt < 4; ++kt) facc = MFMA(rah[kt], wgff[kt], facc);
        if (c < 3) {
#pragma unroll
            for (int r4 = 0; r4 < 4; ++r4)
                fredp[(q * 4 + r4) * 4 + c] = ex2(facc[r4]);
        }
        asm volatile("s_waitcnt lgkmcnt(0)" ::: "memory");
#pragma unroll
        for (int b = 0; b < BT; ++b) {
            const float4 f4 = *reinterpret_cast<const float4*>(&fredp[b * 4]);
            out[((size_t)(b0 + b) * Tn + (Tn - 1)) * Dn + d] =
                bfrd + f4.x * wfr0 + f4.y * wfr1 + f4.z * wfr2;
        }
    }
}

extern "C" void kernel_launch(void* const* d_in, const int* in_sizes, int n_in,
                              void* d_out, int out_size, void* d_ws, size_t ws_size,
                              hipStream_t stream) {
    const float* mu    = (const float*)d_in[0];
    const float* We_ih = (const float*)d_in[1];
    const float* We_hh = (const float*)d_in[2];
    const float* be_ih = (const float*)d_in[3];
    const float* be_hh = (const float*)d_in[4];
    const float* W_ic  = (const float*)d_in[5];
    const float* b_ic  = (const float*)d_in[6];
    const float* Wg_ih = (const float*)d_in[7];
    const float* Wg_hh = (const float*)d_in[8];
    const float* bg_ih = (const float*)d_in[9];
    const float* bg_hh = (const float*)d_in[10];
    const float* W_gf  = (const float*)d_in[11];
    const float* b_gf  = (const float*)d_in[12];
    const float* W_fr  = (const float*)d_in[13];
    const float* b_fr  = (const float*)d_in[14];

    float* h_enc = (float*)d_ws;  // [B, H] f32 = 128 KiB
    float* out = (float*)d_out;

    enc_kernel<<<dim3(Bn / BT), dim3(NTH), 0, stream>>>(mu, We_ih, We_hh, be_ih, be_hh, h_enc);
    gen_kernel<<<dim3(Bn / BT), dim3(NTH), 0, stream>>>(h_enc, W_ic, b_ic, Wg_ih, Wg_hh,
                                                        bg_ih, bg_hh, W_gf, b_gf, W_fr, b_fr, out);
}

// Round 14
// 1401.249 us; speedup vs baseline: 1.0402x; 1.0076x over previous
//
#include <hip/hip_runtime.h>
#include <hip/hip_bf16.h>

#define Bn 256
#define Tn 1024
#define Dn 64
#define Hn 128
#define G3 384
#define ICn 100
#define BT 16
#define NTH 512
#define LDHE 140   // enc hbuf stride (proven fastest for enc, r8/r11)
#define LDHG 136   // gen hbuf stride (16B-aligned reads; proven r7/r10/r11)
#define LDX 72

typedef _Float16 f16;
typedef __attribute__((ext_vector_type(8))) _Float16 f16x8;
typedef __attribute__((ext_vector_type(4))) _Float16 f16x4;
typedef __attribute__((ext_vector_type(4))) float f32x4;

#define MFMA(a, b, c) __builtin_amdgcn_mfma_f32_16x16x32_f16((a), (b), (c), 0, 0, 0)

// gate scales folded into weights/biases: arg_scaled = -arg/ln2 (sigmoid),
// -2*arg/ln2 (tanh) so v_exp (2^x) applies with no range-reduction mul.
#define S_SIG  (-1.4426950408889634f)
#define S_TANH (-2.8853900817779268f)
#define S_EXP  ( 1.4426950408889634f)

__device__ __forceinline__ float rcpa(float x) { return __builtin_amdgcn_rcpf(x); }
__device__ __forceinline__ float ex2(float x) {
#if __has_builtin(__builtin_amdgcn_exp2f)
    return __builtin_amdgcn_exp2f(x);
#else
    return exp2f(x);
#endif
}
__device__ __forceinline__ float sigm2(float x) { return rcpa(1.0f + ex2(x)); }
__device__ __forceinline__ float tanh2(float x) { return fmaf(2.0f, rcpa(1.0f + ex2(x)), -1.0f); }

__device__ __forceinline__ f32x4 splat4(float v) { return (f32x4){v, v, v, v}; }

// LDS-only barrier: orders ds_read/ds_write across the workgroup WITHOUT the
// vmcnt(0) drain __syncthreads() emits. Global loads/stores stay in flight
// across steps (their consumers get compiler-inserted vmcnt waits).
// sched_barrier(0) fences compiler reordering across the asm (rule #18).
__device__ __forceinline__ void bar_lds() {
    __builtin_amdgcn_sched_barrier(0);
    asm volatile("s_waitcnt lgkmcnt(0)" ::: "memory");
    __builtin_amdgcn_s_barrier();
    __builtin_amdgcn_sched_barrier(0);
}

// load a B^T fragment (8 contiguous k) from a row-major f32 weight, scale, cvt f16
__device__ __forceinline__ f16x8 ldw(const float* W, int row, int ldk, int k0, float s) {
    const float* p = W + (size_t)row * ldk + k0;
    f16x8 r;
#pragma unroll
    for (int j = 0; j < 8; ++j) r[j] = (f16)(p[j] * s);
    return r;
}

// ---------------- Encoder GRU (proven ~657us) ----------------
__global__ __launch_bounds__(NTH, 2)
void enc_kernel(const float* __restrict__ mu,
                const float* __restrict__ We_ih, const float* __restrict__ We_hh,
                const float* __restrict__ be_ih, const float* __restrict__ be_hh,
                float* __restrict__ h_enc)
{
    const int b0 = blockIdx.x * BT;
    const int tid = threadIdx.x;
    const int w = tid >> 6, l = tid & 63, c = l & 15, q = l >> 4;

    __shared__ f16 hbuf[2][BT * LDHE];
    __shared__ f16 xstg[2][8][BT * LDX];

    const int gr = w * 16 + c, gz = Hn + w * 16 + c, gn = 2 * Hn + w * 16 + c;

    f16x8 whf[3][4], wxf[3][2];
#pragma unroll
    for (int kt = 0; kt < 4; ++kt) {
        whf[0][kt] = ldw(We_hh, gr, Hn, kt * 32 + q * 8, S_SIG);
        whf[1][kt] = ldw(We_hh, gz, Hn, kt * 32 + q * 8, S_SIG);
        whf[2][kt] = ldw(We_hh, gn, Hn, kt * 32 + q * 8, S_TANH);
    }
#pragma unroll
    for (int kt = 0; kt < 2; ++kt) {
        wxf[0][kt] = ldw(We_ih, gr, Dn, kt * 32 + q * 8, S_SIG);
        wxf[1][kt] = ldw(We_ih, gz, Dn, kt * 32 + q * 8, S_SIG);
        wxf[2][kt] = ldw(We_ih, gn, Dn, kt * 32 + q * 8, S_TANH);
    }
    const float brc = S_SIG * (be_ih[gr] + be_hh[gr]);
    const float bzc = S_SIG * (be_ih[gz] + be_hh[gz]);
    const float bxn = S_TANH * be_ih[gn];
    const float bhn = S_TANH * be_hh[gn];

    float hreg[4];
#pragma unroll
    for (int r4 = 0; r4 < 4; ++r4) hreg[r4] = 0.0f;
    for (int i = tid; i < BT * Hn; i += NTH) hbuf[0][(i >> 7) * LDHE + (i & 127)] = (f16)0.0f;

    const int SIT = (BT * 8 * Dn) / (NTH * 4);  // = 4 staging iters per 8-step chunk
#pragma unroll
    for (int i = 0; i < SIT; ++i) {
        int f = (i * NTH + tid) * 4;
        int t_off = f >> 10, rem = f & 1023;
        int bb = rem >> 6, d = rem & 63;
        const float4 v = *reinterpret_cast<const float4*>(
            mu + ((size_t)(b0 + bb) * Tn + t_off) * Dn + d);
        f16x4 h4; h4[0] = (f16)v.x; h4[1] = (f16)v.y; h4[2] = (f16)v.z; h4[3] = (f16)v.w;
        *reinterpret_cast<f16x4*>(&xstg[0][t_off][bb * LDX + d]) = h4;
    }
    __syncthreads();

    float4 pre[SIT];
    for (int t = 0; t < Tn; ++t) {
        const int ch = t >> 3, s = t & 7, cur = t & 1, sb = ch & 1;
        if (s == 0 && ch + 1 < Tn / 8) {
#pragma unroll
            for (int i = 0; i < SIT; ++i) {
                int f = (i * NTH + tid) * 4;
                int t_off = f >> 10, rem = f & 1023;
                int bb = rem >> 6, d = rem & 63;
                pre[i] = *reinterpret_cast<const float4*>(
                    mu + ((size_t)(b0 + bb) * Tn + (ch + 1) * 8 + t_off) * Dn + d);
            }
        }
        f16x8 ah[4], ax[2];
#pragma unroll
        for (int kt = 0; kt < 4; ++kt)
            ah[kt] = *reinterpret_cast<const f16x8*>(&hbuf[cur][c * LDHE + kt * 32 + q * 8]);
#pragma unroll
        for (int kt = 0; kt < 2; ++kt)
            ax[kt] = *reinterpret_cast<const f16x8*>(&xstg[sb][s][c * LDX + kt * 32 + q * 8]);

        f32x4 acc0 = splat4(brc), acc1 = splat4(bzc);
        f32x4 acc2 = splat4(bhn), accx = splat4(bxn);
        __builtin_amdgcn_s_setprio(1);
#pragma unroll
        for (int kt = 0; kt < 4; ++kt) {
            acc0 = MFMA(ah[kt], whf[0][kt], acc0);
            acc1 = MFMA(ah[kt], whf[1][kt], acc1);
            acc2 = MFMA(ah[kt], whf[2][kt], acc2);
        }
#pragma unroll
        for (int kt = 0; kt < 2; ++kt) {
            acc0 = MFMA(ax[kt], wxf[0][kt], acc0);
            acc1 = MFMA(ax[kt], wxf[1][kt], acc1);
            accx = MFMA(ax[kt], wxf[2][kt], accx);
        }
        __builtin_amdgcn_s_setprio(0);
#pragma unroll
        for (int r4 = 0; r4 < 4; ++r4) {
            float rg = sigm2(acc0[r4]);
            float zg = sigm2(acc1[r4]);
            float ng = tanh2(fmaf(rg, acc2[r4], accx[r4]));
            float hv = fmaf(zg, hreg[r4] - ng, ng);
            hreg[r4] = hv;
            hbuf[cur ^ 1][(q * 4 + r4) * LDHE + w * 16 + c] = (f16)hv;
        }
        if (s == 7 && ch + 1 < Tn / 8) {
#pragma unroll
            for (int i = 0; i < SIT; ++i) {
                int f = (i * NTH + tid) * 4;
                int t_off = f >> 10, rem = f & 1023;
                int bb = rem >> 6, d = rem & 63;
                f16x4 h4;
                h4[0] = (f16)pre[i].x; h4[1] = (f16)pre[i].y;
                h4[2] = (f16)pre[i].z; h4[3] = (f16)pre[i].w;
                *reinterpret_cast<f16x4*>(&xstg[sb ^ 1][t_off][bb * LDX + d]) = h4;
            }
        }
        bar_lds();
    }
#pragma unroll
    for (int r4 = 0; r4 < 4; ++r4)
        h_enc[(size_t)(b0 + q * 4 + r4) * Hn + w * 16 + c] = hreg[r4];
}

// ---------------- Generator GRU (proven ~744us) ----------------
__global__ __launch_bounds__(NTH, 2)
void gen_kernel(const float* __restrict__ h_enc,
                const float* __restrict__ W_ic, const float* __restrict__ b_ic,
                const float* __restrict__ Wg_ih, const float* __restrict__ Wg_hh,
                const float* __restrict__ bg_ih, const float* __restrict__ bg_hh,
                const float* __restrict__ W_gf, const float* __restrict__ b_gf,
                const float* __restrict__ W_fr, const float* __restrict__ b_fr,
                float* __restrict__ out)
{
    const int b0 = blockIdx.x * BT;
    const int tid = threadIdx.x;
    const int w = tid >> 6, l = tid & 63, c = l & 15, q = l >> 4;

    __shared__ f16 hbuf[2][BT * LDHG];
    __shared__ float hencs[BT][Hn];
    __shared__ float ics[BT][ICn];
    __shared__ float xpcs[BT][G3];
    __shared__ float fredB[2][8][BT][4];   // [blk parity][slot][batch][factor]

    for (int i = tid; i < BT * Hn; i += NTH)
        hencs[i >> 7][i & 127] = h_enc[(size_t)(b0 + (i >> 7)) * Hn + (i & 127)];
    __syncthreads();

    for (int i = tid; i < BT * ICn; i += NTH) {
        int bb = i / ICn, j = i - bb * ICn;
        float a = b_ic[j];
        const float* wr = W_ic + (size_t)j * Hn;
#pragma unroll 4
        for (int k = 0; k < Hn; ++k) a = fmaf(wr[k], hencs[bb][k], a);
        ics[bb][j] = a;
    }
    __syncthreads();

    for (int i = tid; i < BT * G3; i += NTH) {
        int g = i >> 4, bb = i & 15;
        float a = bg_ih[g];
        const float* wr = Wg_ih + (size_t)g * ICn;
#pragma unroll 4
        for (int k = 0; k < ICn; ++k) a = fmaf(wr[k], ics[bb][k], a);
        xpcs[bb][g] = a;
    }
    for (int i = tid; i < BT * Hn; i += NTH)
        hbuf[0][(i >> 7) * LDHG + (i & 127)] = (f16)hencs[i >> 7][i & 127];

    const int gr = w * 16 + c, gz = Hn + w * 16 + c, gn = 2 * Hn + w * 16 + c;

    f16x8 whf[3][4];
#pragma unroll
    for (int kt = 0; kt < 4; ++kt) {
        whf[0][kt] = ldw(Wg_hh, gr, Hn, kt * 32 + q * 8, S_SIG);
        whf[1][kt] = ldw(Wg_hh, gz, Hn, kt * 32 + q * 8, S_SIG);
        whf[2][kt] = ldw(Wg_hh, gn, Hn, kt * 32 + q * 8, S_TANH);
    }
    // every wave holds the readout fragments (round-robin), scaled for ex2
    f16x8 wgff[4];
#pragma unroll
    for (int kt = 0; kt < 4; ++kt) {
        if (c < 3) wgff[kt] = ldw(W_gf, c, Hn, kt * 32 + q * 8, S_EXP);
        else {
            f16x8 z;
#pragma unroll
            for (int j = 0; j < 8; ++j) z[j] = (f16)0.0f;
            wgff[kt] = z;
        }
    }
    const float bgfc = (c < 3) ? S_EXP * b_gf[c] : 0.0f;
    const int d = l;
    const float wfr0 = W_fr[d * 3 + 0], wfr1 = W_fr[d * 3 + 1], wfr2 = W_fr[d * 3 + 2];
    const float bfrd = b_fr[d];
    float* op0 = out + ((size_t)(b0 + w) * Tn) * Dn + d;
    float* op1 = out + ((size_t)(b0 + w + 8) * Tn) * Dn + d;

    float hreg[4];
#pragma unroll
    for (int r4 = 0; r4 < 4; ++r4) hreg[r4] = hencs[q * 4 + r4][w * 16 + c];

    __syncthreads();  // xpcs + hbuf[0] ready

    const float bgr = bg_hh[gr], bgz = bg_hh[gz], bhnr = bg_hh[gn];
    f32x4 xrcv, xzcv;
    float xnc[4];
#pragma unroll
    for (int r4 = 0; r4 < 4; ++r4) {
        int bb = q * 4 + r4;
        xrcv[r4] = S_SIG * (xpcs[bb][gr] + bgr);
        xzcv[r4] = S_SIG * (xpcs[bb][gz] + bgz);
        xnc[r4] = S_TANH * xpcs[bb][gn];
    }
    const f32x4 bhnv = splat4(S_TANH * bhnr);
    const f32x4 bgfv = splat4(bgfc);

    auto step = [&](int t, const f16* hb_r, f16* hb_w) {
        const int slot = t & 7, par = (t >> 3) & 1;
        f16x8 ah[4];
#pragma unroll
        for (int kt = 0; kt < 4; ++kt)
            ah[kt] = *reinterpret_cast<const f16x8*>(&hb_r[c * LDHG + kt * 32 + q * 8]);

        f32x4 acc0 = xrcv, acc1 = xzcv, acc2 = bhnv;
        __builtin_amdgcn_s_setprio(1);
#pragma unroll
        for (int kt = 0; kt < 4; ++kt) {
            acc0 = MFMA(ah[kt], whf[0][kt], acc0);
            acc1 = MFMA(ah[kt], whf[1][kt], acc1);
            acc2 = MFMA(ah[kt], whf[2][kt], acc2);
        }
        __builtin_amdgcn_s_setprio(0);
        if (w == slot) {  // round-robin readout wave: factors of h_t -> out row t-1
            f32x4 facc = bgfv;
#pragma unroll
            for (int kt = 0; kt < 4; ++kt) facc = MFMA(ah[kt], wgff[kt], facc);
            if (c < 3) {
#pragma unroll
                for (int r4 = 0; r4 < 4; ++r4)
                    fredB[par][slot][q * 4 + r4][c] = ex2(facc[r4]);
            }
        }
#pragma unroll
        for (int r4 = 0; r4 < 4; ++r4) {
            float rg = sigm2(acc0[r4]);
            float zg = sigm2(acc1[r4]);
            float ng = tanh2(fmaf(rg, acc2[r4], xnc[r4]));
            float hv = fmaf(zg, hreg[r4] - ng, ng);
            hreg[r4] = hv;
            hb_w[(q * 4 + r4) * LDHG + w * 16 + c] = (f16)hv;
        }
        bar_lds();
        if (slot == 7) {  // burst: rates for out rows blk*8-1 .. blk*8+6
            const int base_row = (t >> 3) * 8 - 1;
#pragma unroll
            for (int s = 0; s < 8; ++s) {
                const int r = base_row + s;
                if (r >= 0) {
                    const float4 f0 = *reinterpret_cast<const float4*>(&fredB[par][s][w][0]);
                    op0[(size_t)r * Dn] = bfrd + f0.x * wfr0 + f0.y * wfr1 + f0.z * wfr2;
                    const float4 f1 = *reinterpret_cast<const float4*>(&fredB[par][s][w + 8][0]);
                    op1[(size_t)r * Dn] = bfrd + f1.x * wfr0 + f1.y * wfr1 + f1.z * wfr2;
                }
            }
        }
    };

    for (int tt = 0; tt < Tn; tt += 2) {
        step(tt,     hbuf[0], hbuf[1]);
        step(tt + 1, hbuf[1], hbuf[0]);
    }
    // epilogue: out row 1023 = f(h_1024), h_1024 sits in hbuf[0]
    if (w == 0) {
        f16x8 ah[4];
#pragma unroll
        for (int kt = 0; kt < 4; ++kt)
            ah[kt] = *reinterpret_cast<const f16x8*>(&hbuf[0][c * LDHG + kt * 32 + q * 8]);
        f32x4 facc = bgfv;
#pragma unroll
        for (int kt = 0; kt < 4; ++kt) facc = MFMA(ah[kt], wgff[kt], facc);
        if (c < 3) {
#pragma unroll
            for (int r4 = 0; r4 < 4; ++r4)
                fredB[0][0][q * 4 + r4][c] = ex2(facc[r4]);
        }
    }
    __syncthreads();
    {
        const size_t ofs = (size_t)(Tn - 1) * Dn;
        const float4 f0 = *reinterpret_cast<const float4*>(&fredB[0][0][w][0]);
        op0[ofs] = bfrd + f0.x * wfr0 + f0.y * wfr1 + f0.z * wfr2;
        const float4 f1 = *reinterpret_cast<const float4*>(&fredB[0][0][w + 8][0]);
        op1[ofs] = bfrd + f1.x * wfr0 + f1.y * wfr1 + f1.z * wfr2;
    }
}

extern "C" void kernel_launch(void* const* d_in, const int* in_sizes, int n_in,
                              void* d_out, int out_size, void* d_ws, size_t ws_size,
                              hipStream_t stream) {
    const float* mu    = (const float*)d_in[0];
    const float* We_ih = (const float*)d_in[1];
    const float* We_hh = (const float*)d_in[2];
    const float* be_ih = (const float*)d_in[3];
    const float* be_hh = (const float*)d_in[4];
    const float* W_ic  = (const float*)d_in[5];
    const float* b_ic  = (const float*)d_in[6];
    const float* Wg_ih = (const float*)d_in[7];
    const float* Wg_hh = (const float*)d_in[8];
    const float* bg_ih = (const float*)d_in[9];
    const float* bg_hh = (const float*)d_in[10];
    const float* W_gf  = (const float*)d_in[11];
    const float* b_gf  = (const float*)d_in[12];
    const float* W_fr  = (const float*)d_in[13];
    const float* b_fr  = (const float*)d_in[14];

    float* h_enc = (float*)d_ws;  // [B, H] f32 = 128 KiB
    float* out = (float*)d_out;

    enc_kernel<<<dim3(Bn / BT), dim3(NTH), 0, stream>>>(mu, We_ih, We_hh, be_ih, be_hh, h_enc);
    gen_kernel<<<dim3(Bn / BT), dim3(NTH), 0, stream>>>(h_enc, W_ic, b_ic, Wg_ih, Wg_hh,
                                                        bg_ih, bg_hh, W_gf, b_gf, W_fr, b_fr, out);
}